// Round 7
// baseline (302.653 us; speedup 1.0000x reference)
//
#include <hip/hip_runtime.h>

// LocalityLoss: all four losses reduce to per-(t,h) and per-(t,w) sums of x and
// x^2 over the other axes (n_other = 512*56 = 28672), then prefix/suffix
// cumsums of 56 values per image.
//
// R7: one wave per (t, h, c-quarter). Wave reads one 56-float row per channel
// (224B contiguous, lane=w), 128 independent loads; h fixed -> row bin is a
// scalar pair (one butterfly at wave end), col bin is per-lane (w=lane, no
// cross-lane traffic). No LDS, no barriers, ~24 VGPRs, 28 waves/CU uniform.

constexpr int T = 32, C = 512, H = 56, W = 56;
constexpr int HW = H * W;                 // 3136
constexpr int PH_FLOATS = T * H * 8;      // part_h: [T][H][4 cq][2] = 14336 floats
constexpr float EPS = 1e-6f;

__global__ __launch_bounds__(256) void sums_kernel(const float* __restrict__ x,
                                                   float* __restrict__ part) {
    const int tid  = threadIdx.x;
    const int wave = tid >> 6;
    const int lane = tid & 63;
    // block <-> (t, h); waves cover the 4 c-quarters
    const int bid = blockIdx.x;          // 0..1791
    const int t = bid / H;
    const int h = bid - t * H;
    const int cq = wave;                 // c in [cq*128, cq*128+128)
    const bool act = (lane < W);

    const float* p = x + (size_t)(t * C + cq * 128) * HW + h * W + lane;

    float r0 = 0.f, r1 = 0.f;            // row (h) accumulators
    float c0 = 0.f, c1 = 0.f;            // col (w=lane) accumulators

    #pragma unroll 8
    for (int i = 0; i < 128; ++i) {
        float v = act ? p[(size_t)i * HW] : 0.f;
        float vv = v * v;
        r0 += vv; r1 += v;
        c0 += vv; c1 += v;
    }

    // row: butterfly over all 64 lanes (inactive lanes carry 0)
    #pragma unroll
    for (int m = 1; m < 64; m <<= 1) {
        r0 += __shfl_xor(r0, m, 64);
        r1 += __shfl_xor(r1, m, 64);
    }
    if (lane == 0) {
        float* ph = part + ((size_t)(t * H + h) * 4 + cq) * 2;
        ph[0] = r0;
        ph[1] = r1;
    }
    // col: lane w writes its (sq, lin) pair; slice = (t, h, cq), 112 floats
    if (act) {
        float* pw = part + PH_FLOATS + ((size_t)(t * H + h) * 4 + cq) * 112 + lane * 2;
        pw[0] = c0;
        pw[1] = c1;
    }
}

// One block per image t: build tot[224] = [row sq|row lin|col sq|col lin],
// then compute the per-t loss; 32 atomics total into zeroed out[0].
__global__ __launch_bounds__(256) void reduce_kernel(const float* __restrict__ part,
                                                     float* __restrict__ out) {
    __shared__ float tot[224];
    const int t = blockIdx.x;
    const int tid = threadIdx.x;
    if (tid < 112) {
        // row bins: comp = tid/56 (0=sq,1=lin), h = tid%56; sum 4 cq partials
        int comp = tid / 56, h = tid - comp * 56;
        const float* ph = part + (size_t)(t * H + h) * 8 + comp;
        float s = ph[0] + ph[2] + ph[4] + ph[6];
        tot[comp * 56 + h] = s;
    } else if (tid < 224) {
        // col bins: p = w*2+comp; sum over 224 slices (fully coalesced per slice)
        int p = tid - 112;
        const float* base = part + PH_FLOATS + (size_t)t * 224 * 112;
        float s = 0.f;
        #pragma unroll 8
        for (int sl = 0; sl < 224; ++sl) s += base[(size_t)sl * 112 + p];
        int comp = p & 1, w = p >> 1;
        tot[112 + comp * 56 + w] = s;
    }
    __syncthreads();
    if (tid < 2) {
        // tid 0: rows (h axis); tid 1: cols (w axis)
        const float n_other = 28672.0f;  // 512*56 for both axes
        const float* sq  = &tot[tid * 112];
        const float* lin = &tot[tid * 112 + 56];
        float loss = 0.f;
        float psq = 0.f, plin = 0.f, ssq = 0.f, slin = 0.f;
        for (int i = 0; i < 56; ++i) {
            psq += sq[i];      plin += lin[i];
            ssq += sq[55 - i]; slin += lin[55 - i];
            float n = n_other * (float)(i + 1);
            loss += sqrtf(psq + 2.f * EPS * plin + EPS * EPS * n) + EPS;  // prefix
            loss += sqrtf(ssq + 2.f * EPS * slin + EPS * EPS * n) + EPS;  // suffix
        }
        atomicAdd(out, loss * (1.0f / 128.0f));  // /4 losses, /32 mean over t
    }
}

extern "C" void kernel_launch(void* const* d_in, const int* in_sizes, int n_in,
                              void* d_out, int out_size, void* d_ws, size_t ws_size,
                              hipStream_t stream) {
    const float* x = (const float*)d_in[0];
    float* out = (float*)d_out;
    float* part = (float*)d_ws;  // 14336 + 32*224*112 floats = 3.27 MB

    hipMemsetAsync(out, 0, sizeof(float), stream);
    sums_kernel<<<T * H, 256, 0, stream>>>(x, part);   // 1792 blocks = 7/CU exact
    reduce_kernel<<<T, 256, 0, stream>>>(part, out);
}